// Round 1
// baseline (153.248 us; speedup 1.0000x reference)
//
#include <hip/hip_runtime.h>

#define T_DIM 512
#define B_DIM 16
#define D_DIM 1024
#define WINR  16
#define NW    33   // 2*WINR+1
#define TT    16   // t-tile per block in kernel B

// ---------------- Kernel A: c[t,b] = dot(x[t,b,:], w_seq) ----------------
// One wave (64 lanes) per (t,b) pair; 4 waves per block.
__global__ __launch_bounds__(256) void calc_c_kernel(const float* __restrict__ x,
                                                     const float* __restrict__ w,
                                                     float* __restrict__ c) {
    const int wave = threadIdx.x >> 6;
    const int lane = threadIdx.x & 63;
    const int pair = blockIdx.x * 4 + wave;           // pair = t*B + b
    const float4* x4 = reinterpret_cast<const float4*>(x + (size_t)pair * D_DIM);
    const float4* w4 = reinterpret_cast<const float4*>(w + D_DIM);  // w_seq
    float acc = 0.f;
    #pragma unroll
    for (int i = 0; i < 4; ++i) {
        float4 xv = x4[i * 64 + lane];
        float4 wv = w4[i * 64 + lane];
        acc += xv.x * wv.x + xv.y * wv.y + xv.z * wv.z + xv.w * wv.w;
    }
    #pragma unroll
    for (int off = 32; off; off >>= 1) acc += __shfl_xor(acc, off, 64);
    if (lane == 0) c[pair] = acc;
}

// ------------- Kernel B: softmax over window + gather + concat -------------
// Block handles (b, t0..t0+TT).  256 threads, thread owns float4 at d=4*tid.
// Softmax weights: p[t,w] = softmax_w(c[t-16+w, b]) with invalid -> 0.
// (a[t,b] and bias are constant along w -> cancel in softmax.)
__global__ __launch_bounds__(256) void attn_kernel(const float* __restrict__ x,
                                                   const float* __restrict__ c,
                                                   float* __restrict__ out) {
    __shared__ float pl[TT][NW + 1];
    const int b  = blockIdx.x & (B_DIM - 1);
    const int t0 = (blockIdx.x >> 4) * TT;
    const int tid = threadIdx.x;

    // Phase 1: 16 threads compute the 16 softmax rows into LDS.
    if (tid < TT) {
        const int t = t0 + tid;
        float sc[NW];
        float m = -1e30f;
        #pragma unroll
        for (int w = 0; w < NW; ++w) {
            const int s = t - WINR + w;
            const float v = (s >= 0 && s < T_DIM) ? c[s * B_DIM + b] : -1e30f;
            sc[w] = v;
            m = fmaxf(m, v);
        }
        float sum = 0.f;
        #pragma unroll
        for (int w = 0; w < NW; ++w) {
            const float e = (sc[w] > -1e29f) ? __expf(sc[w] - m) : 0.f;
            sc[w] = e;
            sum += e;
        }
        const float inv = 1.f / sum;
        #pragma unroll
        for (int w = 0; w < NW; ++w) pl[tid][w] = sc[w] * inv;
    }
    __syncthreads();

    // Phase 2: sliding accumulation. Each source row loaded once per block.
    float4 acc[TT];
    #pragma unroll
    for (int j = 0; j < TT; ++j) acc[j] = make_float4(0.f, 0.f, 0.f, 0.f);

    #pragma unroll
    for (int ss = -WINR; ss < TT + WINR; ++ss) {
        const int s = t0 + ss;
        float4 xs = make_float4(0.f, 0.f, 0.f, 0.f);
        if (s >= 0 && s < T_DIM) {
            xs = *reinterpret_cast<const float4*>(
                x + ((size_t)s * B_DIM + b) * D_DIM + tid * 4);
        }
        // Center row doubles as the x-copy half of the output.
        if (ss >= 0 && ss < TT) {
            float* op = out + ((size_t)(t0 + ss) * B_DIM + b) * (2 * D_DIM) + tid * 4;
            *reinterpret_cast<float4*>(op) = xs;
        }
        #pragma unroll
        for (int j = 0; j < TT; ++j) {
            const int w = ss + WINR - j;     // compile-time per (ss, j)
            if (w >= 0 && w < NW) {
                const float pv = pl[j][w];   // wave-uniform broadcast read
                acc[j].x += pv * xs.x;
                acc[j].y += pv * xs.y;
                acc[j].z += pv * xs.z;
                acc[j].w += pv * xs.w;
            }
        }
    }

    // Phase 3: write attention half.
    #pragma unroll
    for (int j = 0; j < TT; ++j) {
        float* op = out + ((size_t)(t0 + j) * B_DIM + b) * (2 * D_DIM) + D_DIM + tid * 4;
        *reinterpret_cast<float4*>(op) = acc[j];
    }
}

extern "C" void kernel_launch(void* const* d_in, const int* in_sizes, int n_in,
                              void* d_out, int out_size, void* d_ws, size_t ws_size,
                              hipStream_t stream) {
    const float* x = (const float*)d_in[0];
    const float* w = (const float*)d_in[1];
    float* c  = (float*)d_ws;                 // T*B floats = 32 KiB scratch
    float* out = (float*)d_out;

    calc_c_kernel<<<(T_DIM * B_DIM) / 4, 256, 0, stream>>>(x, w, c);
    attn_kernel<<<(T_DIM / TT) * B_DIM, 256, 0, stream>>>(x, c, out);
}

// Round 2
// 111.575 us; speedup vs baseline: 1.3735x; 1.3735x over previous
//
#include <hip/hip_runtime.h>

#define T_DIM 512
#define B_DIM 16
#define D_DIM 1024
#define WINR  16
#define NW    33                  // 2*WINR+1
#define TT    16                  // t-rows per block
#define NROWS (TT + 2 * WINR)     // 48 source rows per block

// Fused: c-dot + windowed softmax + gather + concat. One block = (b, 16 t's).
// 256 threads = 4 waves; thread owns float4 at d = 4*tid.
__global__ __launch_bounds__(256, 4) void fused_kernel(const float* __restrict__ x,
                                                       const float* __restrict__ w,
                                                       float* __restrict__ out) {
    // dd[i][j] = softmax weight for output row j from source row (t0-16+i); 0 if outside window.
    __shared__ __align__(16) float dd[NROWS][TT];
    __shared__ float c_loc[NROWS];

    const int b    = blockIdx.x & (B_DIM - 1);
    const int t0   = (blockIdx.x >> 4) * TT;
    const int tid  = threadIdx.x;
    const int wv   = tid >> 6;
    const int lane = tid & 63;
    const size_t rs = (size_t)B_DIM * D_DIM;   // t-stride in floats

    // ---- zero dd (all threads) ----
    {
        float* ddf = &dd[0][0];
        for (int i = tid; i < NROWS * TT; i += 256) ddf[i] = 0.f;
    }

    // ---- phase 0: c_loc[r] = dot(x[t0-16+r, b, :], w_seq), 12 rows per wave ----
    {
        const float4* wseq4 = reinterpret_cast<const float4*>(w + D_DIM);
        const float4 wr0 = wseq4[lane], wr1 = wseq4[lane + 64],
                     wr2 = wseq4[lane + 128], wr3 = wseq4[lane + 192];
        #pragma unroll 2
        for (int k = 0; k < 12; ++k) {
            const int r = wv * 12 + k;
            const int s = t0 - WINR + r;
            float part = 0.f;
            if (s >= 0 && s < T_DIM) {
                const float4* row = reinterpret_cast<const float4*>(
                    x + (size_t)s * rs + (size_t)b * D_DIM);
                const float4 v0 = row[lane], v1 = row[lane + 64],
                             v2 = row[lane + 128], v3 = row[lane + 192];
                part = v0.x * wr0.x + v0.y * wr0.y + v0.z * wr0.z + v0.w * wr0.w
                     + v1.x * wr1.x + v1.y * wr1.y + v1.z * wr1.z + v1.w * wr1.w
                     + v2.x * wr2.x + v2.y * wr2.y + v2.z * wr2.z + v2.w * wr2.w
                     + v3.x * wr3.x + v3.y * wr3.y + v3.z * wr3.z + v3.w * wr3.w;
            }
            #pragma unroll
            for (int off = 32; off; off >>= 1) part += __shfl_xor(part, off, 64);
            if (lane == 0) c_loc[r] = part;
        }
    }
    __syncthreads();

    // ---- phase 1: 16 threads -> softmax rows, scattered into diagonal layout ----
    if (tid < TT) {
        float sc[NW];
        float m = -1e30f;
        #pragma unroll
        for (int ww = 0; ww < NW; ++ww) {
            const int s = t0 + tid - WINR + ww;
            const float v = (s >= 0 && s < T_DIM) ? c_loc[tid + ww] : -1e30f;
            sc[ww] = v;
            m = fmaxf(m, v);
        }
        float sum = 0.f;
        #pragma unroll
        for (int ww = 0; ww < NW; ++ww) {
            const float e = (sc[ww] > -1e29f) ? __expf(sc[ww] - m) : 0.f;
            sc[ww] = e;
            sum += e;
        }
        const float inv = 1.f / sum;
        #pragma unroll
        for (int ww = 0; ww < NW; ++ww) dd[tid + ww][tid] = sc[ww] * inv;
    }
    __syncthreads();

    // ---- phase 2: sliding accumulation; each source row read once per block ----
    float4 acc[TT];
    #pragma unroll
    for (int j = 0; j < TT; ++j) acc[j] = make_float4(0.f, 0.f, 0.f, 0.f);

    const float* xb = x + (size_t)b * D_DIM + (size_t)tid * 4;
    float* ob = out + (size_t)b * 2 * D_DIM + (size_t)tid * 4;

    auto loadrow = [&](int s) -> float4 {
        if (s >= 0 && s < T_DIM)
            return *reinterpret_cast<const float4*>(xb + (size_t)s * rs);
        return make_float4(0.f, 0.f, 0.f, 0.f);
    };

    float4 xs = loadrow(t0 - WINR);
    #pragma unroll 2
    for (int ss = -WINR; ss < TT + WINR; ++ss) {
        const float4 xn = loadrow(t0 + ss + 1);          // prefetch (one-past ok)
        const float4* dr = reinterpret_cast<const float4*>(dd[ss + WINR]);
        const float4 p0 = dr[0], p1 = dr[1], p2 = dr[2], p3 = dr[3];

        if ((unsigned)ss < (unsigned)TT) {               // center row = x-copy half
            *reinterpret_cast<float4*>(ob + (size_t)(t0 + ss) * 2 * rs) = xs;
        }

        #define FMA1(j, pv) \
            acc[j].x += (pv) * xs.x; acc[j].y += (pv) * xs.y; \
            acc[j].z += (pv) * xs.z; acc[j].w += (pv) * xs.w;
        FMA1(0,  p0.x) FMA1(1,  p0.y) FMA1(2,  p0.z) FMA1(3,  p0.w)
        FMA1(4,  p1.x) FMA1(5,  p1.y) FMA1(6,  p1.z) FMA1(7,  p1.w)
        FMA1(8,  p2.x) FMA1(9,  p2.y) FMA1(10, p2.z) FMA1(11, p2.w)
        FMA1(12, p3.x) FMA1(13, p3.y) FMA1(14, p3.z) FMA1(15, p3.w)
        #undef FMA1

        xs = xn;
    }

    // ---- phase 3: attention half ----
    #pragma unroll
    for (int j = 0; j < TT; ++j) {
        *reinterpret_cast<float4*>(ob + (size_t)(t0 + j) * 2 * rs + D_DIM) = acc[j];
    }
}

extern "C" void kernel_launch(void* const* d_in, const int* in_sizes, int n_in,
                              void* d_out, int out_size, void* d_ws, size_t ws_size,
                              hipStream_t stream) {
    const float* x = (const float*)d_in[0];
    const float* w = (const float*)d_in[1];
    float* out = (float*)d_out;
    fused_kernel<<<(T_DIM / TT) * B_DIM, 256, 0, stream>>>(x, w, out);
}